// Round 6
// baseline (49.213 us; speedup 1.0000x reference)
//
#include <hip/hip_runtime.h>
#include <hip/hip_bf16.h>

// Problem: B=4, L=2048, E=512, D=128
//   dep[b,l,d]  = sum_e emb[b,l,e] * W[d,e]
//   dist[b,i,j] = sq[i] + sq[j] - 2 * dep_b . dep_b
// d_out = dep (8192*128 f32) ++ distances (4*2048*2048 f32)
//
// Round 6 ledger:
//   R2->R4: nontemporal stores      = +7us  (reverted R5)
//   R1->R2: gram with no LDS at 2w  = +6us  (reverted R5)
//   R4->R5: swap + float4 + LDS     = -11us
//   NEW: kP2 stages J ONLY (35KB -> 4 blocks/CU), I-frags direct from L2
//        (ping-pong prefetch), mi-major store interleave, XCD swizzle.
//        kP1 reads pre-converted bf16 W (kW).

typedef __attribute__((ext_vector_type(8))) short  short8;   // 8 bf16
typedef __attribute__((ext_vector_type(4))) float  floatx4;  // MFMA C/D frag
typedef __attribute__((ext_vector_type(4))) unsigned short ushortx4;

#define B_  4
#define L_  2048
#define E_  512
#define D_  128
#define M_  (B_*L_)   // 8192

__device__ __forceinline__ unsigned short f2bfu(float x) {
    __hip_bfloat16 h = __float2bfloat16(x);          // HW RNE
    union { __hip_bfloat16 h; unsigned short u; } c; c.h = h; return c.u;
}
__device__ __forceinline__ float bfu2f(unsigned short u) {
    union { unsigned u32; float f; } c; c.u32 = ((unsigned)u) << 16; return c.f;
}
__device__ __forceinline__ short8 cvt8(const float* p) {
    float4 x = *reinterpret_cast<const float4*>(p);
    float4 y = *reinterpret_cast<const float4*>(p + 4);
    short8 t;
    t[0] = (short)f2bfu(x.x); t[1] = (short)f2bfu(x.y);
    t[2] = (short)f2bfu(x.z); t[3] = (short)f2bfu(x.w);
    t[4] = (short)f2bfu(y.x); t[5] = (short)f2bfu(y.y);
    t[6] = (short)f2bfu(y.z); t[7] = (short)f2bfu(y.w);
    return t;
}

// ---------------- kW: W f32 -> bf16 once (256KB -> 128KB) -------------------
__global__ __launch_bounds__(256)
void kW(const float* __restrict__ W, unsigned short* __restrict__ Wb)
{
    int i = (blockIdx.x * 256 + threadIdx.x) * 4;     // 64 blocks cover 65536
    float4 v = *reinterpret_cast<const float4*>(W + i);
    ushort4 u;
    u.x = f2bfu(v.x); u.y = f2bfu(v.y); u.z = f2bfu(v.z); u.w = f2bfu(v.w);
    *reinterpret_cast<ushort4*>(Wb + i) = u;
}

// ---------------- kP1: dep (f32+bf16) + sq; 16 rows per block ---------------
// Swapped operands: A = W-frag, B = emb-frag => lane holds 4 consecutive
// d-cols of one m-row -> float4/ushort4 stores.
__global__ __launch_bounds__(256)
void kP1(const float* __restrict__ emb, const unsigned short* __restrict__ Wb,
         float* __restrict__ dep_out, unsigned short* __restrict__ dep_b16,
         float* __restrict__ sq)
{
    __shared__ float pws[16][4];
    const int tid  = threadIdx.x;
    const int lane = tid & 63, wave = tid >> 6;      // wave owns d-cols wave*32..+31
    const int l15 = lane & 15, lg = lane >> 4;
    const long m0 = (long)blockIdx.x * 16;

    floatx4 acc[2] = { (floatx4){0.f,0.f,0.f,0.f}, (floatx4){0.f,0.f,0.f,0.f} };
    const float* ar = emb + (m0 + l15) * E_;               // B-operand (emb row)
    const unsigned short* w0 = Wb + (wave * 32 + l15) * E_;
    const unsigned short* w1 = Wb + (wave * 32 + 16 + l15) * E_;

    #pragma unroll
    for (int k0 = 0; k0 < E_; k0 += 32) {
        const int kc = k0 + lg * 8;
        short8 bfm = cvt8(ar + kc);
        short8 af0 = *reinterpret_cast<const short8*>(w0 + kc);
        short8 af1 = *reinterpret_cast<const short8*>(w1 + kc);
        acc[0] = __builtin_amdgcn_mfma_f32_16x16x32_bf16(af0, bfm, acc[0], 0, 0, 0);
        acc[1] = __builtin_amdgcn_mfma_f32_16x16x32_bf16(af1, bfm, acc[1], 0, 0, 0);
    }

    const long m = m0 + l15;
    float p = 0.f;
    #pragma unroll
    for (int ni = 0; ni < 2; ++ni) {
        const int dbase = wave * 32 + ni * 16 + lg * 4;
        floatx4  v;
        ushortx4 u;
        #pragma unroll
        for (int j = 0; j < 4; ++j) {
            v[j] = acc[ni][j];
            u[j] = f2bfu(v[j]);
            float vb = bfu2f(u[j]);
            p += vb * vb;               // sq from bf16-rounded dep (matches gram)
        }
        *reinterpret_cast<floatx4*>(dep_out + m * D_ + dbase)  = v;
        *reinterpret_cast<ushortx4*>(dep_b16 + m * D_ + dbase) = u;
    }
    p += __shfl_xor(p, 16);
    p += __shfl_xor(p, 32);
    if (lane < 16) pws[lane][wave] = p;
    __syncthreads();
    if (tid < 16)
        sq[m0 + tid] = pws[tid][0] + pws[tid][1] + pws[tid][2] + pws[tid][3];
}

// ---------------- kP2 v3: dist tile 128x128, J-only LDS, 4 blocks/CU --------
// Swapped operands: A = J-frag (from LDS), B = I-frag (direct from global,
// ping-pong prefetched). mi-major: 16 MFMAs then 4 float4 stores -> stores
// spread across the kernel. XCD-swizzled tile ids for L2 panel locality.
__global__ __launch_bounds__(256, 4)
void kP2(const unsigned short* __restrict__ dep_b16, const float* __restrict__ sq,
         float* __restrict__ dist)
{
    __shared__ __align__(16) unsigned short Js[128][136];   // 34816 B

    const int tid  = threadIdx.x;
    const int lane = tid & 63;
    const int wave = tid >> 6;
    const int wr = wave >> 1, wc = wave & 1;
    const int l15 = lane & 15, lg = lane >> 4;

    // bijective XCD swizzle (1024 blocks, 1024%8==0): XCD x gets 128
    // consecutive tile-ids -> 8 i-panels + 16 j-panels hot in its L2.
    const int swz = (blockIdx.x & 7) * 128 + (blockIdx.x >> 3);
    const int b  = swz >> 8;
    const int i0 = ((swz >> 4) & 15) * 128;
    const int j0 = (swz & 15) * 128;
    const unsigned short* depb = dep_b16 + (long)b * L_ * D_;

    // stage J tile (32 KB), fully coalesced
    #pragma unroll
    for (int jj = 0; jj < 8; ++jj) {
        int chunk = tid + 256 * jj;               // 0..2047
        int row = chunk >> 4, c8 = chunk & 15;
        *reinterpret_cast<short8*>(&Js[row][c8 * 8]) =
            *reinterpret_cast<const short8*>(depb + (long)(j0 + row) * D_ + c8 * 8);
    }

    // I-fragment base: row i0 + wr*64 + mi*16 + l15, col chunk lg*8 + kk*32
    const unsigned short* ibase = depb + (long)(i0 + wr * 64 + l15) * D_ + lg * 8;

    short8 af[2][4];
    #pragma unroll
    for (int kk = 0; kk < 4; ++kk)                 // prefetch mi=0
        af[0][kk] = *reinterpret_cast<const short8*>(ibase + kk * 32);

    const float* sqb = sq + b * L_;
    float sri[4];
    #pragma unroll
    for (int mi = 0; mi < 4; ++mi)
        sri[mi] = sqb[i0 + wr * 64 + mi * 16 + l15];
    floatx4 sqj[4];
    #pragma unroll
    for (int ni = 0; ni < 4; ++ni)
        sqj[ni] = *reinterpret_cast<const floatx4*>(sqb + j0 + wc * 64 + ni * 16 + lg * 4);

    __syncthreads();

    float* db = dist + (long)b * L_ * L_;
    #pragma unroll
    for (int mi = 0; mi < 4; ++mi) {
        if (mi < 3) {                               // prefetch next I-frags
            #pragma unroll
            for (int kk = 0; kk < 4; ++kk)
                af[(mi + 1) & 1][kk] = *reinterpret_cast<const short8*>(
                    ibase + (long)(mi + 1) * 16 * D_ + kk * 32);
        }
        floatx4 acc[4];
        #pragma unroll
        for (int ni = 0; ni < 4; ++ni)
            acc[ni] = (floatx4){0.f, 0.f, 0.f, 0.f};
        #pragma unroll
        for (int ni = 0; ni < 4; ++ni) {
            #pragma unroll
            for (int kk = 0; kk < 4; ++kk) {
                short8 bf = *reinterpret_cast<const short8*>(
                    &Js[wc * 64 + ni * 16 + l15][kk * 32 + lg * 8]);
                acc[ni] = __builtin_amdgcn_mfma_f32_16x16x32_bf16(
                    bf, af[mi & 1][kk], acc[ni], 0, 0, 0);   // swapped A<->B
            }
        }
        const long i = i0 + wr * 64 + mi * 16 + l15;
        #pragma unroll
        for (int ni = 0; ni < 4; ++ni) {
            const int jb = j0 + wc * 64 + ni * 16 + lg * 4;
            floatx4 v;
            #pragma unroll
            for (int jj = 0; jj < 4; ++jj)
                v[jj] = sri[mi] + sqj[ni][jj] - 2.0f * acc[ni][jj];
            *reinterpret_cast<floatx4*>(db + i * L_ + jb) = v;
        }
    }
}

extern "C" void kernel_launch(void* const* d_in, const int* in_sizes, int n_in,
                              void* d_out, int out_size, void* d_ws, size_t ws_size,
                              hipStream_t stream)
{
    const float* emb = (const float*)d_in[0];   // [B,L,E] f32
    const float* W   = (const float*)d_in[1];   // [D,E]   f32

    float* dep_out = (float*)d_out;                       // [B*L, D]
    float* dist    = dep_out + (size_t)M_ * D_;           // [B, L, L]

    unsigned short* dep_b16 = (unsigned short*)d_ws;                          // 2 MB
    float* sq = (float*)((char*)d_ws + (size_t)M_ * D_ * sizeof(unsigned short));
    unsigned short* Wb = (unsigned short*)((char*)sq + (size_t)M_ * sizeof(float));

    hipLaunchKernelGGL(kW,  dim3((D_ * E_) / (256 * 4)), dim3(256), 0, stream, W, Wb);
    hipLaunchKernelGGL(kP1, dim3(M_ / 16), dim3(256), 0, stream,
                       emb, Wb, dep_out, dep_b16, sq);
    hipLaunchKernelGGL(kP2, dim3(16 * 16 * B_), dim3(256), 0, stream,
                       dep_b16, sq, dist);
}